// Round 3
// baseline (54.439 us; speedup 1.0000x reference)
//
#include <hip/hip_runtime.h>

// d2 (B=32, L=2048, K=512) fp32.
// z_t = clip(0.9*z_{t-1} + 0.1*d2_t, 0, 5), z_{-1}=0, scan over t.
//
// Chunked-scan with truncated look-back warmup (0.9^64 ~ 1.2e-3 error,
// threshold 1.63e-2; measured absmax at W=64 was 3.9e-3 -> safe).
//  - float4-width loads/stores along K via clang ext_vector_type
//    (HIP float4 is a struct; __builtin_nontemporal_store needs a real
//    vector type)
//  - NC=16 keeps 1024 waves (4/CU) for latency hiding
//  - nontemporal output stores: don't evict the 128 MB input from the
//    256 MB L3 with the 128 MB output stream -> steady-state fetch ~0.

typedef float f32x4 __attribute__((ext_vector_type(4)));

constexpr int B  = 32;
constexpr int L  = 2048;
constexpr int K  = 512;
constexpr int KV = K / 4;        // float4 columns = 128
constexpr int NC = 16;           // chunks along L
constexpr int C  = L / NC;       // 128
constexpr int W  = 64;           // warmup steps

__global__ __launch_bounds__(256)
void ema_chunk_v4_kernel(const f32x4* __restrict__ d2, f32x4* __restrict__ out) {
    const float lam = 0.9f, om = 0.1f, zmax = 5.0f;

    int tid = blockIdx.x * blockDim.x + threadIdx.x;   // B*NC*KV = 65536
    int k4  = tid & (KV - 1);
    int bc  = tid >> 7;          // / KV
    int c   = bc & (NC - 1);
    int b   = bc >> 4;           // / NC

    const f32x4* in = d2  + (size_t)b * L * KV + k4;
    f32x4*       o  = out + (size_t)b * L * KV + k4;

    int t0 = c * C;
    int tw = t0 - W;
    if (tw < 0) tw = 0;

    float z0 = 0.0f, z1 = 0.0f, z2 = 0.0f, z3 = 0.0f;

    // warmup (no stores)
    #pragma unroll 8
    for (int t = tw; t < t0; ++t) {
        f32x4 d = in[(size_t)t * KV];
        z0 = fminf(fmaxf(lam * z0 + om * d.x, 0.0f), zmax);
        z1 = fminf(fmaxf(lam * z1 + om * d.y, 0.0f), zmax);
        z2 = fminf(fmaxf(lam * z2 + om * d.z, 0.0f), zmax);
        z3 = fminf(fmaxf(lam * z3 + om * d.w, 0.0f), zmax);
    }

    // main chunk
    #pragma unroll 8
    for (int t = t0; t < t0 + C; ++t) {
        f32x4 d = in[(size_t)t * KV];
        z0 = fminf(fmaxf(lam * z0 + om * d.x, 0.0f), zmax);
        z1 = fminf(fmaxf(lam * z1 + om * d.y, 0.0f), zmax);
        z2 = fminf(fmaxf(lam * z2 + om * d.z, 0.0f), zmax);
        z3 = fminf(fmaxf(lam * z3 + om * d.w, 0.0f), zmax);
        f32x4 r = {z0, z1, z2, z3};
        __builtin_nontemporal_store(r, &o[(size_t)t * KV]);
    }
}

extern "C" void kernel_launch(void* const* d_in, const int* in_sizes, int n_in,
                              void* d_out, int out_size, void* d_ws, size_t ws_size,
                              hipStream_t stream) {
    const f32x4* d2 = (const f32x4*)d_in[0];
    f32x4* out = (f32x4*)d_out;

    int total = B * NC * KV;                // 65536 threads
    int block = 256;
    int grid  = total / block;              // 256 blocks
    ema_chunk_v4_kernel<<<grid, block, 0, stream>>>(d2, out);
}

// Round 4
// 53.597 us; speedup vs baseline: 1.0157x; 1.0157x over previous
//
#include <hip/hip_runtime.h>

// d2 (B=32, L=2048, K=512) fp32.
// z_t = clip(0.9*z_{t-1} + 0.1*d2_t, 0, 5), z_{-1}=0, scan over t.
//
// Chunked scan + truncated look-back warmup (W=64: measured absmax 3.9e-3
// vs threshold 1.63e-2). Round-3 design point, from round-1/2 A/B:
//  - parallelism is the lever (2048 waves good, 1024 bad) -> NC=16 with
//    float2 keeps 131072 threads = 2048 waves = 8/CU
//  - float2 (8 B/lane) doubles bytes/instr vs round-1 scalar
//  - unroll 16 -> up to 8 KB in flight per wave (~64 KB/CU)
//  - plain stores (nt showed no FETCH benefit in round 2)

typedef float f32x2 __attribute__((ext_vector_type(2)));

constexpr int B   = 32;
constexpr int L   = 2048;
constexpr int K   = 512;
constexpr int KV2 = K / 2;       // float2 columns = 256
constexpr int NC  = 16;          // chunks along L
constexpr int C   = L / NC;      // 128
constexpr int W   = 64;          // warmup steps

__global__ __launch_bounds__(256)
void ema_chunk_v2_kernel(const f32x2* __restrict__ d2, f32x2* __restrict__ out) {
    const float lam = 0.9f, om = 0.1f, zmax = 5.0f;

    int tid = blockIdx.x * blockDim.x + threadIdx.x;   // B*NC*KV2 = 131072
    int k2  = tid & (KV2 - 1);
    int bc  = tid >> 8;          // / KV2
    int c   = bc & (NC - 1);
    int b   = bc >> 4;           // / NC

    const f32x2* in = d2  + (size_t)b * L * KV2 + k2;
    f32x2*       o  = out + (size_t)b * L * KV2 + k2;

    int t0 = c * C;
    int tw = t0 - W;
    if (tw < 0) tw = 0;

    float z0 = 0.0f, z1 = 0.0f;

    // warmup (no stores)
    #pragma unroll 16
    for (int t = tw; t < t0; ++t) {
        f32x2 d = in[(size_t)t * KV2];
        z0 = fminf(fmaxf(lam * z0 + om * d.x, 0.0f), zmax);
        z1 = fminf(fmaxf(lam * z1 + om * d.y, 0.0f), zmax);
    }

    // main chunk
    #pragma unroll 16
    for (int t = t0; t < t0 + C; ++t) {
        f32x2 d = in[(size_t)t * KV2];
        z0 = fminf(fmaxf(lam * z0 + om * d.x, 0.0f), zmax);
        z1 = fminf(fmaxf(lam * z1 + om * d.y, 0.0f), zmax);
        f32x2 r = {z0, z1};
        o[(size_t)t * KV2] = r;
    }
}

extern "C" void kernel_launch(void* const* d_in, const int* in_sizes, int n_in,
                              void* d_out, int out_size, void* d_ws, size_t ws_size,
                              hipStream_t stream) {
    const f32x2* d2 = (const f32x2*)d_in[0];
    f32x2* out = (f32x2*)d_out;

    int total = B * NC * KV2;               // 131072 threads
    int block = 256;
    int grid  = total / block;              // 512 blocks
    ema_chunk_v2_kernel<<<grid, block, 0, stream>>>(d2, out);
}

// Round 5
// 49.409 us; speedup vs baseline: 1.1018x; 1.0848x over previous
//
#include <hip/hip_runtime.h>

// d2 (B=32, L=2048, K=512) fp32.
// z_t = clip(0.9*z_{t-1} + 0.1*d2_t, 0, 5), z_{-1}=0, scan over t.
//
// Chunked scan + truncated look-back warmup (W=64: measured absmax 3.9e-3
// vs threshold 1.63e-2). Round-4 design point, from r1-r3 A/Bs:
//  - NC=8 (C=256): minimum warmup redundancy (1.25x reads) -> FETCH 80 MB,
//    the best traffic profile measured (r1).
//  - scalar loads keep 131072 threads = 2048 waves = 8/CU (wave count was
//    the r2 regression; redundancy was the r3 regression).
//  - NEW: explicit register double-buffer, depth U=16 -> ~32 loads in
//    flight per wave (8 KB/wave, ~64 KB/CU) instead of compiler's
//    issue-8-then-drain. Attacks the 4.3 TB/s plateau (latency-bound).
//  - warmup+main unified; store predicate (t+u >= t0) is wave-uniform and
//    block-aligned (t0 - tw = 64 = multiple of U), so no divergence.

constexpr int B  = 32;
constexpr int L  = 2048;
constexpr int K  = 512;
constexpr int NC = 8;            // chunks along L
constexpr int C  = L / NC;       // 256
constexpr int W  = 64;           // warmup steps (0.9^64 ~ 1.2e-3)
constexpr int U  = 16;           // prefetch depth (both 256 and 320 are %16==0)

__global__ __launch_bounds__(256)
void ema_prefetch_kernel(const float* __restrict__ d2, float* __restrict__ out) {
    const float lam = 0.9f, om = 0.1f, zmax = 5.0f;

    int tid = blockIdx.x * blockDim.x + threadIdx.x;   // B*NC*K = 131072
    int k   = tid & (K - 1);
    int bc  = tid >> 9;          // / K
    int c   = bc & (NC - 1);
    int b   = bc >> 3;           // / NC

    const float* in = d2  + (size_t)b * L * K + k;
    float*       o  = out + (size_t)b * L * K + k;

    int t0   = c * C;
    int tw   = (c == 0) ? 0 : (t0 - W);
    int tend = t0 + C;

    float z = 0.0f;
    float buf[U];

    // prologue: first U loads in flight
    #pragma unroll
    for (int u = 0; u < U; ++u)
        buf[u] = in[(size_t)(tw + u) * K];

    int t = tw;
    for (; t + U < tend; t += U) {
        // issue next block's loads BEFORE consuming current block
        float nbuf[U];
        #pragma unroll
        for (int u = 0; u < U; ++u)
            nbuf[u] = in[(size_t)(t + U + u) * K];

        #pragma unroll
        for (int u = 0; u < U; ++u) {
            z = fminf(fmaxf(lam * z + om * buf[u], 0.0f), zmax);
            if (t + u >= t0) o[(size_t)(t + u) * K] = z;   // wave-uniform
        }

        #pragma unroll
        for (int u = 0; u < U; ++u) buf[u] = nbuf[u];
    }

    // epilogue: last U (all inside the stored chunk)
    #pragma unroll
    for (int u = 0; u < U; ++u) {
        z = fminf(fmaxf(lam * z + om * buf[u], 0.0f), zmax);
        o[(size_t)(t + u) * K] = z;
    }
}

extern "C" void kernel_launch(void* const* d_in, const int* in_sizes, int n_in,
                              void* d_out, int out_size, void* d_ws, size_t ws_size,
                              hipStream_t stream) {
    const float* d2 = (const float*)d_in[0];
    float* out = (float*)d_out;

    int total = B * NC * K;                 // 131072 threads
    int block = 256;
    int grid  = total / block;              // 512 blocks
    ema_prefetch_kernel<<<grid, block, 0, stream>>>(d2, out);
}